// Round 2
// baseline (356.356 us; speedup 1.0000x reference)
//
#include <hip/hip_runtime.h>
#include <cmath>

#define B_ 32
#define N_ 4096
#define IN_DIM 125
#define ADIM 128
#define KDIM 64
#define DMODEL 1024
#define HID 64
#define KEFF 256
#define EPS_ 1e-6f

// ---------- k0: convert MLP weights to f64 (once per launch) ----------
__global__ __launch_bounds__(256) void k0_cvt(
    const float* __restrict__ W1, const float* __restrict__ b1,
    const float* __restrict__ W2, const float* __restrict__ b2,
    double* __restrict__ W1D, double* __restrict__ b1D,
    double* __restrict__ W2D, double* __restrict__ b2D)
{
  int t = blockIdx.x * 256 + threadIdx.x;
  if (t < IN_DIM * HID) W1D[t] = (double)W1[t];
  if (t < HID) { b1D[t] = (double)b1[t]; W2D[t] = (double)W2[t]; }
  if (t == 0) b2D[0] = (double)b2[0];
}

// ---------- k1: saliency MLP in fp64 (selection-critical) ----------
__global__ __launch_bounds__(256) void k1_saliency(
    const float* __restrict__ x, const double* __restrict__ W1D,
    const double* __restrict__ b1D, const double* __restrict__ W2D,
    const double* __restrict__ b2D, double* __restrict__ salD,
    float* __restrict__ salF)
{
  int pt = blockIdx.x * 256 + threadIdx.x;            // exact grid: B*N
  const float* xr = x + (size_t)pt * IN_DIM;
  double h[HID];
  #pragma unroll
  for (int j = 0; j < HID; ++j) h[j] = b1D[j];
  #pragma unroll 1
  for (int d = 0; d < IN_DIM; ++d) {
    double xv = (double)xr[d];                         // W1D reads are wave-uniform -> s_load
    #pragma unroll
    for (int j = 0; j < HID; ++j) h[j] = fma(xv, W1D[d * HID + j], h[j]);
  }
  double s = b2D[0];
  #pragma unroll
  for (int j = 0; j < HID; ++j) s = fma(fmax(h[j], 0.0), W2D[j], s);
  double sg = 1.0 / (1.0 + exp(-s));
  salD[pt] = sg;
  salF[pt] = (float)sg;
}

// ---- k2: per-batch softmax(sal/0.5) + cumsum(sal)/N, all in fp64 ----
__global__ __launch_bounds__(1024) void k2_softmax_cumsum(
    const double* __restrict__ salD, float* __restrict__ ystarF,
    double* __restrict__ ystarD, float* __restrict__ csal)
{
  __shared__ double red[1024];
  int b = blockIdx.x, t = threadIdx.x;
  const double* s = salD + b * N_;
  double v0 = s[4*t], v1 = s[4*t+1], v2 = s[4*t+2], v3 = s[4*t+3];

  // block max (exact, order-independent)
  double m = fmax(fmax(v0, v1), fmax(v2, v3));
  red[t] = m; __syncthreads();
  for (int off = 512; off > 0; off >>= 1) {
    if (t < off) red[t] = fmax(red[t], red[t + off]);
    __syncthreads();
  }
  double M = red[0]; __syncthreads();

  // exp((v-M)*2): *2 is exact, bitwise == exp(v/lam - M/lam)
  double e0 = exp((v0 - M) * 2.0);
  double e1 = exp((v1 - M) * 2.0);
  double e2 = exp((v2 - M) * 2.0);
  double e3 = exp((v3 - M) * 2.0);
  double se = (e0 + e1) + (e2 + e3);
  red[t] = se; __syncthreads();
  for (int off = 512; off > 0; off >>= 1) {
    if (t < off) red[t] += red[t + off];
    __syncthreads();
  }
  double denom = red[0]; __syncthreads();

  // inclusive scan (Hillis-Steele over thread partials)
  double p0 = v0, p1 = p0 + v1, p2 = p1 + v2, p3 = p2 + v3;
  red[t] = p3; __syncthreads();
  double run = p3;
  for (int off = 1; off < 1024; off <<= 1) {
    double add = (t >= off) ? red[t - off] : 0.0;
    __syncthreads();                  // reads done before writes
    run += add;
    red[t] = run;
    __syncthreads();
  }
  double excl = run - p3;

  int base = b * N_ + 4 * t;
  double y0 = e0 / denom, y1 = e1 / denom, y2 = e2 / denom, y3 = e3 / denom;
  ystarD[base + 0] = y0; ystarF[base + 0] = (float)y0;
  ystarD[base + 1] = y1; ystarF[base + 1] = (float)y1;
  ystarD[base + 2] = y2; ystarF[base + 2] = (float)y2;
  ystarD[base + 3] = y3; ystarF[base + 3] = (float)y3;
  const double invN = 1.0 / 4096.0;   // power of 2: exact
  csal[base + 0] = (float)((excl + p0) * invN);
  csal[base + 1] = (float)((excl + p1) * invN);
  csal[base + 2] = (float)((excl + p2) * invN);
  csal[base + 3] = (float)((excl + p3) * invN);
}

// ---- k3: exact top-k on f64 y_star bits, bitonic, tie -> lower index ----
__global__ __launch_bounds__(1024) void k3_topk(
    const double* __restrict__ ystarD, int* __restrict__ topidx)
{
  __shared__ unsigned long long V[N_];   // f64 bits (y>0: monotone as u64)
  __shared__ unsigned short   I[N_];
  int b = blockIdx.x, t = threadIdx.x;
  const double* y = ystarD + b * N_;
  for (int i = t; i < N_; i += 1024) {
    V[i] = __double_as_longlong(y[i]);
    I[i] = (unsigned short)i;
  }
  __syncthreads();
  for (int k = 2; k <= N_; k <<= 1) {
    for (int j = k >> 1; j > 0; j >>= 1) {
      for (int i = t; i < N_; i += 1024) {
        int l = i ^ j;
        if (l > i) {
          unsigned long long a = V[i], c = V[l];
          unsigned short ai = I[i], ci = I[l];
          // before(p,q): p precedes q in final (value desc, index asc) order
          bool beforeAC = (a > c) || (a == c && ai < ci);
          bool desc = ((i & k) == 0);
          bool sw = desc ? !beforeAC : beforeAC;
          if (sw) { V[i] = c; V[l] = a; I[i] = ci; I[l] = ai; }
        }
      }
      __syncthreads();
    }
  }
  if (t < KEFF) topidx[b * KEFF + t] = (int)I[t];
}

// ---- k4: gather top-256, dense->normalize->lift->proj (fp32) ----
__global__ __launch_bounds__(256) void k4_gather_lift_proj(
    const float* __restrict__ x, const float* __restrict__ sal,
    const float* __restrict__ csal, const int* __restrict__ topidx,
    const float* __restrict__ lift_W, const float* __restrict__ lift_b,
    const float* __restrict__ mu, const float* __restrict__ sigma,
    const float* __restrict__ proj_W, const float* __restrict__ proj_b,
    float* __restrict__ tokens)
{
  __shared__ float sd[16][ADIM];
  __shared__ float sW[ADIM * KDIM];
  __shared__ float scloud[16][KDIM];
  __shared__ float snf[16];
  __shared__ int sidx[16];

  int t = threadIdx.x;
  int bid = blockIdx.x;
  int b = bid >> 4;
  int p0 = (bid & 15) * 16;

  if (t < 16) sidx[t] = topidx[b * KEFF + p0 + t];
  for (int e = t; e < ADIM * KDIM; e += 256) sW[e] = lift_W[e];
  __syncthreads();

  for (int e = t; e < 16 * ADIM; e += 256) {
    int p = e >> 7, a = e & 127;
    int n = sidx[p];
    int base = b * N_ + n;
    float v;
    if (a < IN_DIM)          v = x[(size_t)base * IN_DIM + a];
    else if (a == IN_DIM)    v = sal[base];
    else if (a == IN_DIM+1)  v = (float)n / (float)(N_ - 1);
    else                     v = csal[base];
    sd[p][a] = v;
  }
  __syncthreads();

  {
    int p = t >> 4, l16 = t & 15;
    float ss = 0.f;
    for (int a = l16; a < ADIM; a += 16) { float v = sd[p][a]; ss = fmaf(v, v, ss); }
    ss += __shfl_down(ss, 8);
    ss += __shfl_down(ss, 4);
    ss += __shfl_down(ss, 2);
    ss += __shfl_down(ss, 1);
    if (l16 == 0) snf[p] = 1.f / (sqrtf(ss) + EPS_);
  }
  __syncthreads();

  for (int e = t; e < 16 * ADIM; e += 256) {
    int p = e >> 7, a = e & 127;
    sd[p][a] = (sd[p][a] * snf[p] - mu[a]) / sigma[a];
  }
  __syncthreads();

  int wv = t >> 6, lane = t & 63;
  for (int q = 0; q < 4; ++q) {
    int p = q * 4 + wv;
    float acc = lift_b[lane];
    #pragma unroll
    for (int a = 0; a < ADIM; ++a)
      acc = fmaf(sd[p][a], sW[a * KDIM + lane], acc);
    scloud[p][lane] = acc;
  }
  __syncthreads();

  float ac[64];
  #pragma unroll
  for (int i = 0; i < 64; ++i) ac[i] = 0.f;
  #pragma unroll 1
  for (int c = 0; c < KDIM; ++c) {
    float w0 = proj_W[c * DMODEL + t];
    float w1 = proj_W[c * DMODEL + t + 256];
    float w2 = proj_W[c * DMODEL + t + 512];
    float w3 = proj_W[c * DMODEL + t + 768];
    #pragma unroll
    for (int p = 0; p < 16; ++p) {
      float cv = scloud[p][c];
      ac[p*4+0] = fmaf(cv, w0, ac[p*4+0]);
      ac[p*4+1] = fmaf(cv, w1, ac[p*4+1]);
      ac[p*4+2] = fmaf(cv, w2, ac[p*4+2]);
      ac[p*4+3] = fmaf(cv, w3, ac[p*4+3]);
    }
  }
  float pb0 = proj_b[t], pb1 = proj_b[t+256], pb2 = proj_b[t+512], pb3 = proj_b[t+768];
  for (int p = 0; p < 16; ++p) {
    int ro = (b * KEFF + p0 + p) * DMODEL;
    tokens[ro + t      ] = ac[p*4+0] + pb0;
    tokens[ro + t + 256] = ac[p*4+1] + pb1;
    tokens[ro + t + 512] = ac[p*4+2] + pb2;
    tokens[ro + t + 768] = ac[p*4+3] + pb3;
  }
}

extern "C" void kernel_launch(void* const* d_in, const int* in_sizes, int n_in,
                              void* d_out, int out_size, void* d_ws, size_t ws_size,
                              hipStream_t stream)
{
  const float* x      = (const float*)d_in[0];
  const float* W1     = (const float*)d_in[1];
  const float* b1     = (const float*)d_in[2];
  const float* W2     = (const float*)d_in[3];
  const float* b2     = (const float*)d_in[4];
  const float* lift_W = (const float*)d_in[5];
  const float* lift_b = (const float*)d_in[6];
  const float* mu     = (const float*)d_in[7];
  const float* sigma  = (const float*)d_in[8];
  const float* proj_W = (const float*)d_in[9];
  const float* proj_b = (const float*)d_in[10];

  float* tokens = (float*)d_out;                        // [B,256,1024]
  float* ystarF = tokens + (size_t)B_ * KEFF * DMODEL;  // [B,N]

  // workspace layout (all 8-byte aligned; ~3.2 MB total)
  double* salD   = (double*)d_ws;                 // B*N
  double* ystarD = salD + (size_t)B_ * N_;        // B*N
  double* W1D    = ystarD + (size_t)B_ * N_;      // 8000
  double* b1D    = W1D + IN_DIM * HID;            // 64
  double* W2D    = b1D + HID;                     // 64
  double* b2D    = W2D + HID;                     // 1
  float*  salF   = (float*)(b2D + 1);             // B*N
  float*  csalF  = salF + (size_t)B_ * N_;        // B*N
  int*    topidx = (int*)(csalF + (size_t)B_ * N_); // B*256

  k0_cvt<<<(IN_DIM * HID + 255) / 256, 256, 0, stream>>>(
      W1, b1, W2, b2, W1D, b1D, W2D, b2D);
  k1_saliency<<<(B_ * N_) / 256, 256, 0, stream>>>(
      x, W1D, b1D, W2D, b2D, salD, salF);
  k2_softmax_cumsum<<<B_, 1024, 0, stream>>>(salD, ystarF, ystarD, csalF);
  k3_topk<<<B_, 1024, 0, stream>>>(ystarD, topidx);
  k4_gather_lift_proj<<<(B_ * KEFF) / 16, 256, 0, stream>>>(
      x, salF, csalF, topidx, lift_W, lift_b, mu, sigma, proj_W, proj_b, tokens);
}

// Round 3
// 287.999 us; speedup vs baseline: 1.2374x; 1.2374x over previous
//
#include <hip/hip_runtime.h>
#include <cmath>

#define B_ 32
#define N_ 4096
#define IN_DIM 125
#define ADIM 128
#define KDIM 64
#define DMODEL 1024
#define HID 64
#define KEFF 256
#define EPS_ 1e-6f

// ---------- k0: convert MLP weights to f64 (once per launch) ----------
__global__ __launch_bounds__(256) void k0_cvt(
    const float* __restrict__ W1, const float* __restrict__ b1,
    const float* __restrict__ W2, const float* __restrict__ b2,
    double* __restrict__ W1D, double* __restrict__ b1D,
    double* __restrict__ W2D, double* __restrict__ b2D)
{
  int t = blockIdx.x * 256 + threadIdx.x;
  if (t < IN_DIM * HID) W1D[t] = (double)W1[t];
  if (t < HID) { b1D[t] = (double)b1[t]; W2D[t] = (double)W2[t]; }
  if (t == 0) b2D[0] = (double)b2[0];
}

// ---------- k1: saliency MLP in fp64, spill-free ----------
// 8 waves/block; wave w owns j in [8w,8w+8) (scalar W1 loads); each lane
// owns 2 points -> 16 f64 acc = 32 VGPRs. x staged in LDS (stride 125:
// 2-way bank aliasing = free).
#define K1_PTS 128
__global__ __launch_bounds__(512) void k1_saliency(
    const float* __restrict__ x, const double* __restrict__ W1D,
    const double* __restrict__ b1D, const double* __restrict__ W2D,
    const double* __restrict__ b2D, double* __restrict__ salD,
    float* __restrict__ salF)
{
  __shared__ double smem[8000];              // 64,000 B (xs overlay + reduce)
  float* xs = (float*)smem;                  // [128][125] flat
  int tid = threadIdx.x;
  int p0 = blockIdx.x * K1_PTS;

  // stage x tile: 16000 floats = 4000 float4 (base 64000*bid -> 16B aligned)
  {
    const float4* src = (const float4*)(x + (size_t)p0 * IN_DIM);
    float4* dst = (float4*)xs;
    for (int e = tid; e < (K1_PTS * IN_DIM) / 4; e += 512) dst[e] = src[e];
  }
  __syncthreads();

  int wv = __builtin_amdgcn_readfirstlane(tid >> 6);   // provably uniform
  int lane = tid & 63;
  int jb = wv * 8;

  double acc0[8], acc1[8];
  #pragma unroll
  for (int jj = 0; jj < 8; ++jj) { acc0[jj] = b1D[jb + jj]; acc1[jj] = acc0[jj]; }

  const float* xr0 = xs + lane * IN_DIM;
  const float* xr1 = xs + (lane + 64) * IN_DIM;
  for (int d = 0; d < IN_DIM; ++d) {
    double xd0 = (double)xr0[d];
    double xd1 = (double)xr1[d];
    const double* wrow = W1D + d * HID + jb;           // uniform -> s_load
    #pragma unroll
    for (int jj = 0; jj < 8; ++jj) {
      double w = wrow[jj];
      acc0[jj] = fma(xd0, w, acc0[jj]);
      acc1[jj] = fma(xd1, w, acc1[jj]);
    }
  }

  double part0 = 0.0, part1 = 0.0;
  #pragma unroll
  for (int jj = 0; jj < 8; ++jj) {
    double w2 = W2D[jb + jj];
    part0 = fma(fmax(acc0[jj], 0.0), w2, part0);
    part1 = fma(fmax(acc1[jj], 0.0), w2, part1);
  }
  __syncthreads();                            // xs reads complete
  double* red = smem;                         // [8][128] overlay
  red[wv * K1_PTS + lane] = part0;
  red[wv * K1_PTS + lane + 64] = part1;
  __syncthreads();
  if (tid < K1_PTS) {
    double s = b2D[0];
    #pragma unroll
    for (int w = 0; w < 8; ++w) s += red[w * K1_PTS + tid];
    double sg = 1.0 / (1.0 + exp(-s));
    salD[p0 + tid] = sg;                      // f64 sort key (monotone == y*)
    salF[p0 + tid] = (float)sg;
  }
}

// ---- k2: per-batch softmax(sal/0.5) + cumsum(sal)/N, fp32, shfl-based ----
// (values only need fp32; SELECTION uses salD in k3, so no f64 needed here)
__global__ __launch_bounds__(256) void k2_softmax_cumsum(
    const float* __restrict__ salF, float* __restrict__ ystar,
    float* __restrict__ csal)
{
  __shared__ float wmax[4], wsum[4], wtot[4];
  int b = blockIdx.x, t = threadIdx.x, lane = t & 63, wv = t >> 6;
  const float4* s4 = (const float4*)(salF + (size_t)b * N_);
  float v[16];
  #pragma unroll
  for (int k = 0; k < 4; ++k) {
    float4 a = s4[t * 4 + k];
    v[4*k] = a.x; v[4*k+1] = a.y; v[4*k+2] = a.z; v[4*k+3] = a.w;
  }
  // block max
  float m = v[0];
  #pragma unroll
  for (int i = 1; i < 16; ++i) m = fmaxf(m, v[i]);
  #pragma unroll
  for (int off = 32; off > 0; off >>= 1) m = fmaxf(m, __shfl_down(m, off));
  if (lane == 0) wmax[wv] = m;
  __syncthreads();
  float M = fmaxf(fmaxf(wmax[0], wmax[1]), fmaxf(wmax[2], wmax[3]));

  // exp((v-M)*2) and block sum
  float e[16];
  float se = 0.f;
  #pragma unroll
  for (int i = 0; i < 16; ++i) { e[i] = expf((v[i] - M) * 2.0f); se += e[i]; }
  float ss = se;
  #pragma unroll
  for (int off = 32; off > 0; off >>= 1) ss += __shfl_down(ss, off);
  if (lane == 0) wsum[wv] = ss;
  __syncthreads();
  float denom = (wsum[0] + wsum[1]) + (wsum[2] + wsum[3]);
  float rdenom = 1.f / denom;

  // inclusive scan of v (contiguous 16 per thread)
  float p[16];
  p[0] = v[0];
  #pragma unroll
  for (int i = 1; i < 16; ++i) p[i] = p[i-1] + v[i];
  float T = p[15];
  float incl = T;
  #pragma unroll
  for (int off = 1; off < 64; off <<= 1) {
    float nv = __shfl_up(incl, off);
    if (lane >= off) incl += nv;
  }
  float wexcl = incl - T;
  if (lane == 63) wtot[wv] = incl;
  __syncthreads();
  float woff = 0.f;
  for (int w = 0; w < 4; ++w) if (w < wv) woff += wtot[w];
  float base = woff + wexcl;

  float4* y4 = (float4*)(ystar + (size_t)b * N_);
  float4* c4 = (float4*)(csal + (size_t)b * N_);
  const float invN = 1.f / (float)N_;
  #pragma unroll
  for (int k = 0; k < 4; ++k) {
    float4 yo, co;
    yo.x = e[4*k]   * rdenom; co.x = (base + p[4*k])   * invN;
    yo.y = e[4*k+1] * rdenom; co.y = (base + p[4*k+1]) * invN;
    yo.z = e[4*k+2] * rdenom; co.z = (base + p[4*k+2]) * invN;
    yo.w = e[4*k+3] * rdenom; co.w = (base + p[4*k+3]) * invN;
    y4[t * 4 + k] = yo;
    c4[t * 4 + k] = co;
  }
}

// ---- k3a: sort 512-elem chunks desc on salD bits, keep top-256 ----
// prec(a,b): key desc, tie -> lower index (matches lax.top_k).
__global__ __launch_bounds__(256) void k3a_sortchunks(
    const double* __restrict__ salD, unsigned long long* __restrict__ candK,
    int* __restrict__ candI)
{
  __shared__ unsigned long long K[512];
  __shared__ int I[512];
  int bid = blockIdx.x, t = threadIdx.x;
  int b = bid >> 3, c = bid & 7;
  const double* y = salD + (size_t)b * N_ + c * 512;
  for (int i = t; i < 512; i += 256) {
    K[i] = __double_as_longlong(y[i]);      // y in (0,1): bits monotone
    I[i] = c * 512 + i;
  }
  __syncthreads();
  for (int k = 2; k <= 512; k <<= 1) {
    for (int j = k >> 1; j > 0; j >>= 1) {
      for (int i = t; i < 512; i += 256) {
        int l = i ^ j;
        if (l > i) {
          unsigned long long a = K[i], cc = K[l];
          int ai = I[i], ci = I[l];
          bool prec = (a > cc) || (a == cc && ai < ci);
          bool up = ((i & k) == 0);
          if (up ? !prec : prec) { K[i] = cc; K[l] = a; I[i] = ci; I[l] = ai; }
        }
      }
      __syncthreads();
    }
  }
  if (t < 256) {
    candK[(b * 8 + c) * 256 + t] = K[t];
    candI[(b * 8 + c) * 256 + t] = I[t];
  }
}

// ---- k3b: merge 8 sorted top-256 lists -> global sorted top-256 ----
__global__ __launch_bounds__(256) void k3b_merge(
    const unsigned long long* __restrict__ candK, const int* __restrict__ candI,
    int* __restrict__ topidx)
{
  __shared__ unsigned long long K[2048];
  __shared__ int I[2048];
  int b = blockIdx.x, t = threadIdx.x;
  // region r: [list 2r desc] ++ [list 2r+1 reversed] -> bitonic 512
  for (int i = t; i < 2048; i += 256) {
    int r = i >> 9, o = i & 511;
    int lst = (o < 256) ? 2 * r : 2 * r + 1;
    int pos = (o < 256) ? o : 511 - o;
    K[i] = candK[(b * 8 + lst) * 256 + pos];
    I[i] = candI[(b * 8 + lst) * 256 + pos];
  }
  __syncthreads();

  #define CMPSWAP(i, l) { \
    unsigned long long a = K[i], cc = K[l]; \
    int ai = I[i], ci = I[l]; \
    bool prec = (a > cc) || (a == cc && ai < ci); \
    if (!prec) { K[i] = cc; K[l] = a; I[i] = ci; I[l] = ai; } }

  // round 1: merge all four 512-regions in parallel
  for (int j = 256; j > 0; j >>= 1) {
    for (int i = t; i < 2048; i += 256) {
      int l = i ^ j;
      if (l > i) CMPSWAP(i, l);
    }
    __syncthreads();
  }
  // round 2: pair (0,1)->base 0, (2,3)->base 1024
  for (int i = t; i < 512; i += 256) {
    int pr = i >> 8, o = i & 255;
    int dst = pr * 1024 + 256 + o, src = pr * 1024 + 512 + 255 - o;
    K[dst] = K[src]; I[dst] = I[src];
  }
  __syncthreads();
  for (int j = 256; j > 0; j >>= 1) {
    for (int ii = t; ii < 1024; ii += 256) {
      int i = (ii < 512) ? ii : (ii + 512);   // blocks at 0 and 1024
      int l = i ^ j;
      if (l > i) CMPSWAP(i, l);
    }
    __syncthreads();
  }
  // round 3: [0,256) with reversed top-256 of block at 1024
  for (int i = t; i < 256; i += 256) {
    K[256 + i] = K[1024 + 255 - i]; I[256 + i] = I[1024 + 255 - i];
  }
  __syncthreads();
  for (int j = 256; j > 0; j >>= 1) {
    for (int i = t; i < 512; i += 256) {
      int l = i ^ j;
      if (l > i) CMPSWAP(i, l);
    }
    __syncthreads();
  }
  if (t < 256) topidx[b * KEFF + t] = I[t];
  #undef CMPSWAP
}

// ---- k4: gather top-256, dense->normalize->lift->proj (fp32) ----
__global__ __launch_bounds__(256) void k4_gather_lift_proj(
    const float* __restrict__ x, const float* __restrict__ sal,
    const float* __restrict__ csal, const int* __restrict__ topidx,
    const float* __restrict__ lift_W, const float* __restrict__ lift_b,
    const float* __restrict__ mu, const float* __restrict__ sigma,
    const float* __restrict__ proj_W, const float* __restrict__ proj_b,
    float* __restrict__ tokens)
{
  __shared__ float sd[16][ADIM];
  __shared__ float sW[ADIM * KDIM];
  __shared__ float scloud[16][KDIM];
  __shared__ float snf[16];
  __shared__ int sidx[16];

  int t = threadIdx.x;
  int bid = blockIdx.x;
  int b = bid >> 4;
  int p0 = (bid & 15) * 16;

  if (t < 16) sidx[t] = topidx[b * KEFF + p0 + t];
  for (int e = t; e < ADIM * KDIM; e += 256) sW[e] = lift_W[e];
  __syncthreads();

  for (int e = t; e < 16 * ADIM; e += 256) {
    int p = e >> 7, a = e & 127;
    int n = sidx[p];
    int base = b * N_ + n;
    float v;
    if (a < IN_DIM)          v = x[(size_t)base * IN_DIM + a];
    else if (a == IN_DIM)    v = sal[base];
    else if (a == IN_DIM+1)  v = (float)n / (float)(N_ - 1);
    else                     v = csal[base];
    sd[p][a] = v;
  }
  __syncthreads();

  {
    int p = t >> 4, l16 = t & 15;
    float ss = 0.f;
    for (int a = l16; a < ADIM; a += 16) { float v = sd[p][a]; ss = fmaf(v, v, ss); }
    ss += __shfl_down(ss, 8);
    ss += __shfl_down(ss, 4);
    ss += __shfl_down(ss, 2);
    ss += __shfl_down(ss, 1);
    if (l16 == 0) snf[p] = 1.f / (sqrtf(ss) + EPS_);
  }
  __syncthreads();

  for (int e = t; e < 16 * ADIM; e += 256) {
    int p = e >> 7, a = e & 127;
    sd[p][a] = (sd[p][a] * snf[p] - mu[a]) / sigma[a];
  }
  __syncthreads();

  int wv = t >> 6, lane = t & 63;
  for (int q = 0; q < 4; ++q) {
    int p = q * 4 + wv;
    float acc = lift_b[lane];
    #pragma unroll
    for (int a = 0; a < ADIM; ++a)
      acc = fmaf(sd[p][a], sW[a * KDIM + lane], acc);
    scloud[p][lane] = acc;
  }
  __syncthreads();

  float ac[64];
  #pragma unroll
  for (int i = 0; i < 64; ++i) ac[i] = 0.f;
  #pragma unroll 1
  for (int c = 0; c < KDIM; ++c) {
    float w0 = proj_W[c * DMODEL + t];
    float w1 = proj_W[c * DMODEL + t + 256];
    float w2 = proj_W[c * DMODEL + t + 512];
    float w3 = proj_W[c * DMODEL + t + 768];
    #pragma unroll
    for (int p = 0; p < 16; ++p) {
      float cv = scloud[p][c];
      ac[p*4+0] = fmaf(cv, w0, ac[p*4+0]);
      ac[p*4+1] = fmaf(cv, w1, ac[p*4+1]);
      ac[p*4+2] = fmaf(cv, w2, ac[p*4+2]);
      ac[p*4+3] = fmaf(cv, w3, ac[p*4+3]);
    }
  }
  float pb0 = proj_b[t], pb1 = proj_b[t+256], pb2 = proj_b[t+512], pb3 = proj_b[t+768];
  for (int p = 0; p < 16; ++p) {
    int ro = (b * KEFF + p0 + p) * DMODEL;
    tokens[ro + t      ] = ac[p*4+0] + pb0;
    tokens[ro + t + 256] = ac[p*4+1] + pb1;
    tokens[ro + t + 512] = ac[p*4+2] + pb2;
    tokens[ro + t + 768] = ac[p*4+3] + pb3;
  }
}

extern "C" void kernel_launch(void* const* d_in, const int* in_sizes, int n_in,
                              void* d_out, int out_size, void* d_ws, size_t ws_size,
                              hipStream_t stream)
{
  const float* x      = (const float*)d_in[0];
  const float* W1     = (const float*)d_in[1];
  const float* b1     = (const float*)d_in[2];
  const float* W2     = (const float*)d_in[3];
  const float* b2     = (const float*)d_in[4];
  const float* lift_W = (const float*)d_in[5];
  const float* lift_b = (const float*)d_in[6];
  const float* mu     = (const float*)d_in[7];
  const float* sigma  = (const float*)d_in[8];
  const float* proj_W = (const float*)d_in[9];
  const float* proj_b = (const float*)d_in[10];

  float* tokens = (float*)d_out;                        // [B,256,1024]
  float* ystarF = tokens + (size_t)B_ * KEFF * DMODEL;  // [B,N]

  // workspace (8-byte entities first)
  double* salD   = (double*)d_ws;                           // B*N
  double* W1D    = salD + (size_t)B_ * N_;                  // 8000
  double* b1D    = W1D + IN_DIM * HID;                      // 64
  double* W2D    = b1D + HID;                               // 64
  double* b2D    = W2D + HID;                               // 1 (+7 pad)
  unsigned long long* candK = (unsigned long long*)(b2D + 8); // 32*2048
  float*  salF   = (float*)(candK + (size_t)B_ * 2048);     // B*N
  float*  csalF  = salF + (size_t)B_ * N_;                  // B*N
  int*    candI  = (int*)(csalF + (size_t)B_ * N_);         // 32*2048
  int*    topidx = candI + (size_t)B_ * 2048;               // B*256

  k0_cvt<<<(IN_DIM * HID + 255) / 256, 256, 0, stream>>>(
      W1, b1, W2, b2, W1D, b1D, W2D, b2D);
  k1_saliency<<<(B_ * N_) / K1_PTS, 512, 0, stream>>>(
      x, W1D, b1D, W2D, b2D, salD, salF);
  k2_softmax_cumsum<<<B_, 256, 0, stream>>>(salF, ystarF, csalF);
  k3a_sortchunks<<<B_ * 8, 256, 0, stream>>>(salD, candK, candI);
  k3b_merge<<<B_, 256, 0, stream>>>(candK, candI, topidx);
  k4_gather_lift_proj<<<(B_ * KEFF) / 16, 256, 0, stream>>>(
      x, salF, csalF, topidx, lift_W, lift_b, mu, sigma, proj_W, proj_b, tokens);
}

// Round 4
// 254.005 us; speedup vs baseline: 1.4029x; 1.1338x over previous
//
#include <hip/hip_runtime.h>
#include <cmath>

#define B_ 32
#define N_ 4096
#define IN_DIM 125
#define ADIM 128
#define KDIM 64
#define DMODEL 1024
#define HID 64
#define KEFF 256
#define EPS_ 1e-6f

// ---------- k0: convert MLP weights to f64 (once per launch) ----------
__global__ __launch_bounds__(256) void k0_cvt(
    const float* __restrict__ W1, const float* __restrict__ b1,
    const float* __restrict__ W2, const float* __restrict__ b2,
    double* __restrict__ W1D, double* __restrict__ b1D,
    double* __restrict__ W2D, double* __restrict__ b2D)
{
  int t = blockIdx.x * 256 + threadIdx.x;
  if (t < IN_DIM * HID) W1D[t] = (double)W1[t];
  if (t < HID) { b1D[t] = (double)b1[t]; W2D[t] = (double)W2[t]; }
  if (t == 0) b2D[0] = (double)b2[0];
}

// ---------- k1: saliency MLP in fp64, 100% occupancy + pipelined ----------
// 64 points/block, 512 threads (8 waves). Wave w owns j-octet [8w,8w+8);
// lane owns 1 point -> 8 f64 acc = 16 VGPR. W1 rows double-buffered in
// SGPRs (uniform s_load) so the next row loads during the current FMA burst.
// LDS 32KB -> 4 blocks/CU * 8 waves = 32 waves/CU.
#define K1_PTS 64
__global__ __launch_bounds__(512) void k1_saliency(
    const float* __restrict__ x, const double* __restrict__ W1D,
    const double* __restrict__ b1D, const double* __restrict__ W2D,
    const double* __restrict__ b2D, double* __restrict__ salD,
    float* __restrict__ salF)
{
  __shared__ double smem[4008];              // 32064 B (xs + red overlay)
  float* xs = (float*)smem;                  // [64][125]
  int tid = threadIdx.x;
  int p0 = blockIdx.x * K1_PTS;

  { // stage x tile: 8000 floats = 2000 float4 (byte base 32000*bid: 16B aligned)
    const float4* src = (const float4*)(x + (size_t)p0 * IN_DIM);
    float4* dst = (float4*)xs;
    for (int e = tid; e < (K1_PTS * IN_DIM) / 4; e += 512) dst[e] = src[e];
  }
  __syncthreads();

  int wv = __builtin_amdgcn_readfirstlane(tid >> 6);
  int lane = tid & 63;
  int jb = wv * 8;

  double acc[8];
  #pragma unroll
  for (int jj = 0; jj < 8; ++jj) acc[jj] = b1D[jb + jj];

  const float* xr = xs + lane * IN_DIM;      // stride 125 dwords: 2-way = free
  double wA[8], wB[8];
  #pragma unroll
  for (int jj = 0; jj < 8; ++jj) wA[jj] = W1D[jb + jj];    // row 0
  float xv0 = xr[0];

  #pragma unroll 1
  for (int d = 0; d < 124; d += 2) {
    float xv1 = xr[d + 1];
    #pragma unroll
    for (int jj = 0; jj < 8; ++jj) wB[jj] = W1D[(d + 1) * HID + jb + jj];
    double xd0 = (double)xv0;
    #pragma unroll
    for (int jj = 0; jj < 8; ++jj) acc[jj] = fma(xd0, wA[jj], acc[jj]);
    xv0 = xr[d + 2];
    #pragma unroll
    for (int jj = 0; jj < 8; ++jj) wA[jj] = W1D[(d + 2) * HID + jb + jj];
    double xd1 = (double)xv1;
    #pragma unroll
    for (int jj = 0; jj < 8; ++jj) acc[jj] = fma(xd1, wB[jj], acc[jj]);
  }
  { // d = 124 (wA holds row 124)
    double xd = (double)xv0;
    #pragma unroll
    for (int jj = 0; jj < 8; ++jj) acc[jj] = fma(xd, wA[jj], acc[jj]);
  }

  double part = 0.0;
  #pragma unroll
  for (int jj = 0; jj < 8; ++jj)
    part = fma(fmax(acc[jj], 0.0), W2D[jb + jj], part);
  __syncthreads();                           // xs reads done
  double* red = smem;                        // [8][64] overlay
  red[wv * K1_PTS + lane] = part;
  __syncthreads();
  if (tid < K1_PTS) {
    double s = b2D[0];
    #pragma unroll
    for (int w = 0; w < 8; ++w) s += red[w * K1_PTS + tid];
    double sg = 1.0 / (1.0 + exp(-s));
    salD[p0 + tid] = sg;                     // f64 sort key (monotone == y*)
    salF[p0 + tid] = (float)sg;
  }
}

// ---- k2: per-batch softmax(sal/0.5) + cumsum(sal)/N, fp32, shfl-based ----
__global__ __launch_bounds__(256) void k2_softmax_cumsum(
    const float* __restrict__ salF, float* __restrict__ ystar,
    float* __restrict__ csal)
{
  __shared__ float wmax[4], wsum[4], wtot[4];
  int b = blockIdx.x, t = threadIdx.x, lane = t & 63, wv = t >> 6;
  const float4* s4 = (const float4*)(salF + (size_t)b * N_);
  float v[16];
  #pragma unroll
  for (int k = 0; k < 4; ++k) {
    float4 a = s4[t * 4 + k];
    v[4*k] = a.x; v[4*k+1] = a.y; v[4*k+2] = a.z; v[4*k+3] = a.w;
  }
  float m = v[0];
  #pragma unroll
  for (int i = 1; i < 16; ++i) m = fmaxf(m, v[i]);
  #pragma unroll
  for (int off = 32; off > 0; off >>= 1) m = fmaxf(m, __shfl_down(m, off));
  if (lane == 0) wmax[wv] = m;
  __syncthreads();
  float M = fmaxf(fmaxf(wmax[0], wmax[1]), fmaxf(wmax[2], wmax[3]));

  float e[16];
  float se = 0.f;
  #pragma unroll
  for (int i = 0; i < 16; ++i) { e[i] = expf((v[i] - M) * 2.0f); se += e[i]; }
  float ss = se;
  #pragma unroll
  for (int off = 32; off > 0; off >>= 1) ss += __shfl_down(ss, off);
  if (lane == 0) wsum[wv] = ss;
  __syncthreads();
  float denom = (wsum[0] + wsum[1]) + (wsum[2] + wsum[3]);
  float rdenom = 1.f / denom;

  float p[16];
  p[0] = v[0];
  #pragma unroll
  for (int i = 1; i < 16; ++i) p[i] = p[i-1] + v[i];
  float T = p[15];
  float incl = T;
  #pragma unroll
  for (int off = 1; off < 64; off <<= 1) {
    float nv = __shfl_up(incl, off);
    if (lane >= off) incl += nv;
  }
  float wexcl = incl - T;
  if (lane == 63) wtot[wv] = incl;
  __syncthreads();
  float woff = 0.f;
  for (int w = 0; w < 4; ++w) if (w < wv) woff += wtot[w];
  float base = woff + wexcl;

  float4* y4 = (float4*)(ystar + (size_t)b * N_);
  float4* c4 = (float4*)(csal + (size_t)b * N_);
  const float invN = 1.f / (float)N_;
  #pragma unroll
  for (int k = 0; k < 4; ++k) {
    float4 yo, co;
    yo.x = e[4*k]   * rdenom; co.x = (base + p[4*k])   * invN;
    yo.y = e[4*k+1] * rdenom; co.y = (base + p[4*k+1]) * invN;
    yo.z = e[4*k+2] * rdenom; co.z = (base + p[4*k+2]) * invN;
    yo.w = e[4*k+3] * rdenom; co.w = (base + p[4*k+3]) * invN;
    y4[t * 4 + k] = yo;
    c4[t * 4 + k] = co;
  }
}

// ---- k3a: sort 512-elem chunks desc on salD bits, keep top-256 ----
__global__ __launch_bounds__(256) void k3a_sortchunks(
    const double* __restrict__ salD, unsigned long long* __restrict__ candK,
    int* __restrict__ candI)
{
  __shared__ unsigned long long K[512];
  __shared__ int I[512];
  int bid = blockIdx.x, t = threadIdx.x;
  int b = bid >> 3, c = bid & 7;
  const double* y = salD + (size_t)b * N_ + c * 512;
  for (int i = t; i < 512; i += 256) {
    K[i] = __double_as_longlong(y[i]);      // y in (0,1): bits monotone
    I[i] = c * 512 + i;
  }
  __syncthreads();
  for (int k = 2; k <= 512; k <<= 1) {
    for (int j = k >> 1; j > 0; j >>= 1) {
      for (int i = t; i < 512; i += 256) {
        int l = i ^ j;
        if (l > i) {
          unsigned long long a = K[i], cc = K[l];
          int ai = I[i], ci = I[l];
          bool prec = (a > cc) || (a == cc && ai < ci);
          bool up = ((i & k) == 0);
          if (up ? !prec : prec) { K[i] = cc; K[l] = a; I[i] = ci; I[l] = ai; }
        }
      }
      __syncthreads();
    }
  }
  if (t < 256) {
    candK[(b * 8 + c) * 256 + t] = K[t];
    candI[(b * 8 + c) * 256 + t] = I[t];
  }
}

// ---- k3b: merge 8 sorted top-256 lists -> global sorted top-256 ----
__global__ __launch_bounds__(256) void k3b_merge(
    const unsigned long long* __restrict__ candK, const int* __restrict__ candI,
    int* __restrict__ topidx)
{
  __shared__ unsigned long long K[2048];
  __shared__ int I[2048];
  int b = blockIdx.x, t = threadIdx.x;
  for (int i = t; i < 2048; i += 256) {
    int r = i >> 9, o = i & 511;
    int lst = (o < 256) ? 2 * r : 2 * r + 1;
    int pos = (o < 256) ? o : 511 - o;
    K[i] = candK[(b * 8 + lst) * 256 + pos];
    I[i] = candI[(b * 8 + lst) * 256 + pos];
  }
  __syncthreads();

  #define CMPSWAP(i, l) { \
    unsigned long long a = K[i], cc = K[l]; \
    int ai = I[i], ci = I[l]; \
    bool prec = (a > cc) || (a == cc && ai < ci); \
    if (!prec) { K[i] = cc; K[l] = a; I[i] = ci; I[l] = ai; } }

  for (int j = 256; j > 0; j >>= 1) {
    for (int i = t; i < 2048; i += 256) {
      int l = i ^ j;
      if (l > i) CMPSWAP(i, l);
    }
    __syncthreads();
  }
  for (int i = t; i < 512; i += 256) {
    int pr = i >> 8, o = i & 255;
    int dst = pr * 1024 + 256 + o, src = pr * 1024 + 512 + 255 - o;
    K[dst] = K[src]; I[dst] = I[src];
  }
  __syncthreads();
  for (int j = 256; j > 0; j >>= 1) {
    for (int ii = t; ii < 1024; ii += 256) {
      int i = (ii < 512) ? ii : (ii + 512);
      int l = i ^ j;
      if (l > i) CMPSWAP(i, l);
    }
    __syncthreads();
  }
  for (int i = t; i < 256; i += 256) {
    K[256 + i] = K[1024 + 255 - i]; I[256 + i] = I[1024 + 255 - i];
  }
  __syncthreads();
  for (int j = 256; j > 0; j >>= 1) {
    for (int i = t; i < 512; i += 256) {
      int l = i ^ j;
      if (l > i) CMPSWAP(i, l);
    }
    __syncthreads();
  }
  if (t < 256) topidx[b * KEFF + t] = I[t];
  #undef CMPSWAP
}

// ---- k4a: gather top-32/block, dense->normalize->lift -> cloud[8192][64] ----
__global__ __launch_bounds__(256) void k4a_lift(
    const float* __restrict__ x, const float* __restrict__ sal,
    const float* __restrict__ csal, const int* __restrict__ topidx,
    const float* __restrict__ lift_W, const float* __restrict__ lift_b,
    const float* __restrict__ mu, const float* __restrict__ sigma,
    float* __restrict__ cloud)
{
  __shared__ float sd[32][ADIM];      // 16KB
  __shared__ float sW[ADIM * KDIM];   // 32KB
  __shared__ float snf[32];
  __shared__ int sidx[32];

  int t = threadIdx.x, bid = blockIdx.x;
  int b = bid >> 3, p0 = (bid & 7) * 32;

  if (t < 32) sidx[t] = topidx[b * KEFF + p0 + t];
  for (int e = t; e < ADIM * KDIM; e += 256) sW[e] = lift_W[e];
  __syncthreads();

  for (int e = t; e < 32 * ADIM; e += 256) {
    int p = e >> 7, a = e & 127;
    int n = sidx[p];
    int base = b * N_ + n;
    float v;
    if (a < IN_DIM)          v = x[(size_t)base * IN_DIM + a];
    else if (a == IN_DIM)    v = sal[base];
    else if (a == IN_DIM+1)  v = (float)n / (float)(N_ - 1);
    else                     v = csal[base];
    sd[p][a] = v;
  }
  __syncthreads();

  { // norms: 8 lanes per point (8-aligned groups within wave)
    int p = t >> 3, l8 = t & 7;
    float ss = 0.f;
    for (int a = l8; a < ADIM; a += 8) { float v = sd[p][a]; ss = fmaf(v, v, ss); }
    ss += __shfl_down(ss, 4);
    ss += __shfl_down(ss, 2);
    ss += __shfl_down(ss, 1);
    if (l8 == 0) snf[p] = 1.f / (sqrtf(ss) + EPS_);
  }
  __syncthreads();

  for (int e = t; e < 32 * ADIM; e += 256) {
    int p = e >> 7, a = e & 127;
    sd[p][a] = (sd[p][a] * snf[p] - mu[a]) / sigma[a];
  }
  __syncthreads();

  // lift: wave wv owns 8 points; lane = output dim k
  int wv = t >> 6, lane = t & 63;
  float acc[8];
  float lb = lift_b[lane];
  #pragma unroll
  for (int q = 0; q < 8; ++q) acc[q] = lb;
  #pragma unroll 1
  for (int a = 0; a < ADIM; a += 4) {
    float wl0 = sW[a*KDIM+lane],     wl1 = sW[(a+1)*KDIM+lane];
    float wl2 = sW[(a+2)*KDIM+lane], wl3 = sW[(a+3)*KDIM+lane];
    #pragma unroll
    for (int q = 0; q < 8; ++q) {
      int p = wv * 8 + q;
      acc[q] = fmaf(sd[p][a],   wl0, acc[q]);
      acc[q] = fmaf(sd[p][a+1], wl1, acc[q]);
      acc[q] = fmaf(sd[p][a+2], wl2, acc[q]);
      acc[q] = fmaf(sd[p][a+3], wl3, acc[q]);
    }
  }
  #pragma unroll
  for (int q = 0; q < 8; ++q) {
    int gp = b * KEFF + p0 + wv * 8 + q;
    cloud[(size_t)gp * KDIM + lane] = acc[q];    // coalesced 64 dwords
  }
}

// ---- k4b: proj GEMM. Block = 32 points x 256 cols; 1024 blocks. ----
// cloud tile in LDS (broadcast reads), proj_W rows double-buffered in regs.
__global__ __launch_bounds__(256) void k4b_proj(
    const float* __restrict__ cloud, const float* __restrict__ proj_W,
    const float* __restrict__ proj_b, float* __restrict__ tokens)
{
  __shared__ float sc[32][KDIM];      // 8KB
  int t = threadIdx.x;
  int pg = blockIdx.x >> 2, cg = blockIdx.x & 3;

  { // load cloud tile: 2048 floats = 512 float4
    const float4* src = (const float4*)(cloud + (size_t)pg * 32 * KDIM);
    float4* dst = (float4*)sc;
    dst[t] = src[t];
    dst[t + 256] = src[t + 256];
  }
  __syncthreads();

  int col = cg * 256 + t;
  float acc[32];
  #pragma unroll
  for (int p = 0; p < 32; ++p) acc[p] = 0.f;

  float4 wcur;
  wcur.x = proj_W[0*DMODEL + col]; wcur.y = proj_W[1*DMODEL + col];
  wcur.z = proj_W[2*DMODEL + col]; wcur.w = proj_W[3*DMODEL + col];
  #pragma unroll 1
  for (int c = 0; c < KDIM; c += 4) {
    float4 wnext = {0.f, 0.f, 0.f, 0.f};
    if (c + 4 < KDIM) {
      wnext.x = proj_W[(size_t)(c+4)*DMODEL + col];
      wnext.y = proj_W[(size_t)(c+5)*DMODEL + col];
      wnext.z = proj_W[(size_t)(c+6)*DMODEL + col];
      wnext.w = proj_W[(size_t)(c+7)*DMODEL + col];
    }
    #pragma unroll
    for (int p = 0; p < 32; ++p) {
      float4 cv = *(const float4*)&sc[p][c];     // broadcast b128
      acc[p] = fmaf(cv.x, wcur.x, acc[p]);
      acc[p] = fmaf(cv.y, wcur.y, acc[p]);
      acc[p] = fmaf(cv.z, wcur.z, acc[p]);
      acc[p] = fmaf(cv.w, wcur.w, acc[p]);
    }
    wcur = wnext;
  }

  float pb = proj_b[col];
  int gp0 = pg * 32;
  #pragma unroll
  for (int p = 0; p < 32; ++p)
    tokens[(size_t)(gp0 + p) * DMODEL + col] = acc[p] + pb;
}

extern "C" void kernel_launch(void* const* d_in, const int* in_sizes, int n_in,
                              void* d_out, int out_size, void* d_ws, size_t ws_size,
                              hipStream_t stream)
{
  const float* x      = (const float*)d_in[0];
  const float* W1     = (const float*)d_in[1];
  const float* b1     = (const float*)d_in[2];
  const float* W2     = (const float*)d_in[3];
  const float* b2     = (const float*)d_in[4];
  const float* lift_W = (const float*)d_in[5];
  const float* lift_b = (const float*)d_in[6];
  const float* mu     = (const float*)d_in[7];
  const float* sigma  = (const float*)d_in[8];
  const float* proj_W = (const float*)d_in[9];
  const float* proj_b = (const float*)d_in[10];

  float* tokens = (float*)d_out;                        // [B,256,1024]
  float* ystarF = tokens + (size_t)B_ * KEFF * DMODEL;  // [B,N]

  // workspace layout with overlay:
  //   [0, 2MB): salD(1MB) | candK(512K) | candI(256K)   -- all dead after k3b
  //             cloud(2MB) overlays this region (written by k4a)
  //   [2MB, ...): W1D/b1D/W2D/b2D (~65KB) | salF(512K) | csalF(512K) | topidx(32K)
  char* wsb = (char*)d_ws;
  double* salD   = (double*)wsb;                                   // B*N f64
  unsigned long long* candK = (unsigned long long*)(wsb + (1<<20));
  int*    candI  = (int*)(wsb + (1<<20) + (512<<10));
  float*  cloud  = (float*)wsb;                                    // overlay
  double* W1D    = (double*)(wsb + (2<<20));
  double* b1D    = W1D + IN_DIM * HID;
  double* W2D    = b1D + HID;
  double* b2D    = W2D + HID;
  float*  salF   = (float*)(wsb + (2<<20) + 65536);
  float*  csalF  = salF + (size_t)B_ * N_;
  int*    topidx = (int*)(csalF + (size_t)B_ * N_);

  k0_cvt<<<(IN_DIM * HID + 255) / 256, 256, 0, stream>>>(
      W1, b1, W2, b2, W1D, b1D, W2D, b2D);
  k1_saliency<<<(B_ * N_) / K1_PTS, 512, 0, stream>>>(
      x, W1D, b1D, W2D, b2D, salD, salF);
  k2_softmax_cumsum<<<B_, 256, 0, stream>>>(salF, ystarF, csalF);
  k3a_sortchunks<<<B_ * 8, 256, 0, stream>>>(salD, candK, candI);
  k3b_merge<<<B_, 256, 0, stream>>>(candK, candI, topidx);
  k4a_lift<<<B_ * 8, 256, 0, stream>>>(
      x, salF, csalF, topidx, lift_W, lift_b, mu, sigma, cloud);
  k4b_proj<<<(B_ * KEFF / 32) * (DMODEL / 256), 256, 0, stream>>>(
      cloud, proj_W, proj_b, tokens);
}